// Round 7
// baseline (347.011 us; speedup 1.0000x reference)
//
#include <hip/hip_runtime.h>

#define DIM 1024
#define NH 16
#define HD 64
#define BATCH 16
#define SEQ 512
#define MROWS (BATCH*SEQ)   // 8192

using u16 = unsigned short;
using u32 = unsigned int;
typedef __attribute__((ext_vector_type(8))) u16 u16x8;
typedef __attribute__((ext_vector_type(4))) u16 u16x4;
typedef __attribute__((ext_vector_type(8))) __bf16 bf16x8;
typedef __attribute__((ext_vector_type(4))) float f32x4;
typedef __attribute__((ext_vector_type(4))) float float4v;

__device__ __forceinline__ float bf2f(u16 h) {
  unsigned u = ((unsigned)h) << 16;
  union { unsigned u; float f; } v; v.u = u; return v.f;
}
__device__ __forceinline__ u16 f2bf(float f) {
  union { float f; unsigned u; } v; v.f = f;
  unsigned u = v.u + 0x7fffu + ((v.u >> 16) & 1u);
  return (u16)(u >> 16);
}
// granule swizzle for 64-u16 rows (8 granules of 16B)
__device__ __forceinline__ int swz(int r) { return (r & 7) ^ (r >> 3); }

// async global->LDS, 16B per lane. LDS dest must be wave-uniform base + lane*16.
__device__ __forceinline__ void gld_lds16(const u16* g, u16* l) {
  __builtin_amdgcn_global_load_lds(
      (const __attribute__((address_space(1))) void*)g,
      (__attribute__((address_space(3))) void*)l, 16, 0, 0);
}

__device__ __forceinline__ f32x4 mfma16(u16x8 a, u16x8 b, f32x4 c) {
  return __builtin_amdgcn_mfma_f32_16x16x32_bf16(
      __builtin_bit_cast(bf16x8, a), __builtin_bit_cast(bf16x8, b), c, 0, 0, 0);
}

// ---------------- fp32 -> bf16 conversion ----------------
__global__ void f32_to_bf16_kernel(const float* __restrict__ in, u16* __restrict__ out, int n) {
  int i = (blockIdx.x * blockDim.x + threadIdx.x) * 4;
  if (i >= n) return;
  float4v v = *(const float4v*)(in + i);
  u16x4 o;
  o.x = f2bf(v.x); o.y = f2bf(v.y); o.z = f2bf(v.z); o.w = f2bf(v.w);
  *(u16x4*)(out + i) = o;
}

// fused conversion of the 4 weight matrices (outputs contiguous in ws)
__global__ void wconv_kernel(const float* __restrict__ Wq, const float* __restrict__ Wk,
                             const float* __restrict__ Wv, const float* __restrict__ Wo,
                             u16* __restrict__ out) {
  const float* in = (blockIdx.z == 0) ? Wq : (blockIdx.z == 1) ? Wk
                   : (blockIdx.z == 2) ? Wv : Wo;
  int i = (blockIdx.x * blockDim.x + threadIdx.x) * 4;
  float4v v = *(const float4v*)(in + i);
  u16x4 o;
  o.x = f2bf(v.x); o.y = f2bf(v.y); o.z = f2bf(v.z); o.w = f2bf(v.w);
  *(u16x4*)(out + (size_t)blockIdx.z * (DIM * DIM) + i) = o;
}

// ---------------- RoPE tables: [SEQ][32] cos/sin ----------------
__global__ void rope_tables_kernel(float* __restrict__ ctab, float* __restrict__ stab) {
  int t = blockIdx.x * blockDim.x + threadIdx.x;  // SEQ*32
  int s = t >> 5, j = t & 31;
  float invf = powf(10000.f, -(float)j / 32.f);
  float a = (float)s * invf;
  ctab[t] = cosf(a);
  stab[t] = sinf(a);
}

// ---------------- RoPE applied in-place to q and k (bf16) ----------------
__global__ void rope_kernel(u16* __restrict__ Q, u16* __restrict__ K,
                            const float* __restrict__ ctab, const float* __restrict__ stab) {
  int t = blockIdx.x * blockDim.x + threadIdx.x;  // 524288 per tensor
  u16* X = blockIdx.z ? K : Q;
  int j = t & 3;
  int h = (t >> 2) & 15;
  int m = t >> 6;
  int s = m & (SEQ - 1);
  u16* base = X + (size_t)m * DIM + h * HD + j * 8;
  u16x8 lo = *(u16x8*)base;
  u16x8 hi = *(u16x8*)(base + 32);
  const float* cp = ctab + s * 32 + j * 8;
  const float* sp = stab + s * 32 + j * 8;
  u16x8 lo2, hi2;
#pragma unroll
  for (int i = 0; i < 8; i++) {
    float c = cp[i], sn = sp[i];
    float xl = bf2f(lo[i]), xh = bf2f(hi[i]);
    lo2[i] = f2bf(xl * c - xh * sn);
    hi2[i] = f2bf(xh * c + xl * sn);
  }
  *(u16x8*)base = lo2;
  *(u16x8*)(base + 32) = hi2;
}

// ---------------- GEMM 128x128 tile, BK=64, swizzled LDS, XCD-chunked ----------------
// C[m][n] = sum_k A[m][k]*B[n][k].
#define BM 128
#define BN 128

// fused QKV: Bw = [3072][1024]; output select by column block
__global__ __launch_bounds__(256, 4) void gemm_qkv(const u16* __restrict__ A,
                                                   const u16* __restrict__ Bw,
                                                   u16* __restrict__ Cq, u16* __restrict__ Ck,
                                                   u16* __restrict__ Cv) {
  __shared__ alignas(16) u16 As[BM * 64];
  __shared__ alignas(16) u16 Bs[BN * 64];
  const int K = DIM, N = DIM;
  // XCD-chunked swizzle: nwg=1536, chunk=192, NBX=24
  const int orig = blockIdx.x;
  const int id2 = (orig & 7) * 192 + (orig >> 3);
  const int m0 = (id2 / 24) * BM;
  const int n0g = (id2 % 24) * BN;                 // 0..3071
  u16* C = (n0g < 1024) ? Cq : (n0g < 2048) ? Ck : Cv;
  const int n0 = n0g & 1023;
  const int tid = threadIdx.x, lane = tid & 63;
  const int w = tid >> 6, wr = w >> 1, wc = w & 1;
  const int lr = lane & 15, kgrp = lane >> 4;

  f32x4 acc[4][4] = {};

  for (int kt = 0; kt < K; kt += 64) {
#pragma unroll
    for (int i = 0; i < 4; i++) {                  // A: 1024 granules of 16B
      int c = tid + i * 256;
      int r_ = c >> 3, p = c & 7;
      gld_lds16(A + (size_t)(m0 + r_) * K + kt + ((p ^ (r_ & 7)) << 3), &As[c * 8]);
    }
#pragma unroll
    for (int i = 0; i < 4; i++) {                  // B: 1024 granules of 16B
      int c = tid + i * 256;
      int r_ = c >> 3, p = c & 7;
      gld_lds16(Bw + (size_t)(n0g + r_) * K + kt + ((p ^ (r_ & 7)) << 3), &Bs[c * 8]);
    }
    __syncthreads();
#pragma unroll
    for (int half = 0; half < 2; half++) {
      u16x8 a[4], b[4];
      int g = half * 4 + kgrp;
#pragma unroll
      for (int i = 0; i < 4; i++) {
        int row = wr * 64 + i * 16 + lr;
        a[i] = *(const u16x8*)(&As[row * 64 + ((g ^ (row & 7)) << 3)]);
      }
#pragma unroll
      for (int j = 0; j < 4; j++) {
        int row = wc * 64 + j * 16 + lr;
        b[j] = *(const u16x8*)(&Bs[row * 64 + ((g ^ (row & 7)) << 3)]);
      }
#pragma unroll
      for (int i = 0; i < 4; i++)
#pragma unroll
        for (int j = 0; j < 4; j++)
          acc[i][j] = mfma16(a[i], b[j], acc[i][j]);
    }
    __syncthreads();
  }

#pragma unroll
  for (int i = 0; i < 4; i++) {
    int grow = m0 + wr * 64 + i * 16 + kgrp * 4;
#pragma unroll
    for (int j = 0; j < 4; j++) {
      int gcol = n0 + wc * 64 + j * 16 + lr;
#pragma unroll
      for (int r = 0; r < 4; r++)
        C[(size_t)(grow + r) * N + gcol] = f2bf(acc[i][j][r]);
    }
  }
}

// out projection: C fp32 [8192][1024]; nwg=512, chunk=64, NBX=8
__global__ __launch_bounds__(256, 4) void gemm_out(const u16* __restrict__ A,
                                                   const u16* __restrict__ B,
                                                   float* __restrict__ C) {
  __shared__ alignas(16) u16 As[BM * 64];
  __shared__ alignas(16) u16 Bs[BN * 64];
  const int K = DIM, N = DIM;
  const int orig = blockIdx.x;
  const int id2 = (orig & 7) * 64 + (orig >> 3);
  const int m0 = (id2 >> 3) * BM;
  const int n0 = (id2 & 7) * BN;
  const int tid = threadIdx.x, lane = tid & 63;
  const int w = tid >> 6, wr = w >> 1, wc = w & 1;
  const int lr = lane & 15, kgrp = lane >> 4;

  f32x4 acc[4][4] = {};

  for (int kt = 0; kt < K; kt += 64) {
#pragma unroll
    for (int i = 0; i < 4; i++) {
      int c = tid + i * 256;
      int r_ = c >> 3, p = c & 7;
      gld_lds16(A + (size_t)(m0 + r_) * K + kt + ((p ^ (r_ & 7)) << 3), &As[c * 8]);
    }
#pragma unroll
    for (int i = 0; i < 4; i++) {
      int c = tid + i * 256;
      int r_ = c >> 3, p = c & 7;
      gld_lds16(B + (size_t)(n0 + r_) * K + kt + ((p ^ (r_ & 7)) << 3), &Bs[c * 8]);
    }
    __syncthreads();
#pragma unroll
    for (int half = 0; half < 2; half++) {
      u16x8 a[4], b[4];
      int g = half * 4 + kgrp;
#pragma unroll
      for (int i = 0; i < 4; i++) {
        int row = wr * 64 + i * 16 + lr;
        a[i] = *(const u16x8*)(&As[row * 64 + ((g ^ (row & 7)) << 3)]);
      }
#pragma unroll
      for (int j = 0; j < 4; j++) {
        int row = wc * 64 + j * 16 + lr;
        b[j] = *(const u16x8*)(&Bs[row * 64 + ((g ^ (row & 7)) << 3)]);
      }
#pragma unroll
      for (int i = 0; i < 4; i++)
#pragma unroll
        for (int j = 0; j < 4; j++)
          acc[i][j] = mfma16(a[i], b[j], acc[i][j]);
    }
    __syncthreads();
  }

#pragma unroll
  for (int i = 0; i < 4; i++) {
    int grow = m0 + wr * 64 + i * 16 + kgrp * 4;
#pragma unroll
    for (int j = 0; j < 4; j++) {
      int gcol = n0 + wc * 64 + j * 16 + lr;
#pragma unroll
      for (int r = 0; r < 4; r++)
        C[(size_t)(grow + r) * N + gcol] = acc[i][j][r];
    }
  }
}

// ---------------- Flash attention v3 (causal), swizzled LDS, low-VGPR ----------------
// 1D grid 2048 (XCD-chunked). Block: 256 threads = 4 waves; wave w owns 16 q rows.
__global__ __launch_bounds__(256, 5) void attn_kernel(const u16* __restrict__ Q,
                                                      const u16* __restrict__ K,
                                                      const u16* __restrict__ V,
                                                      u16* __restrict__ O) {
  __shared__ alignas(16) u16 Ks[64 * 64];
  __shared__ alignas(16) u16 Vs[64 * 64];
  __shared__ alignas(16) u16 Vt[64 * 64];
  __shared__ alignas(16) u16 Ps[4][16 * 64];

  const int orig = blockIdx.x;                 // 2048 blocks
  const int id2 = (orig & 7) * 256 + (orig >> 3);
  const int qt = id2 & 7, bh = id2 >> 3;
  const int b = bh >> 4, h = bh & 15;
  const int tid = threadIdx.x, lane = tid & 63, w = tid >> 6;
  const int lr = lane & 15, kgrp = lane >> 4, koff = kgrp * 8;
  const int q0 = qt * 64;
  const int va = tid >> 3;          // kv-pair index 0..31 (transpose role)
  const int vd = tid & 7;           // d granule 0..7

  // Q fragments, held in registers the whole kernel
  const u16* qptr = Q + ((size_t)(b * SEQ + q0 + w * 16 + lr)) * DIM + h * HD;
  u16x8 qf0 = *(const u16x8*)(qptr + koff);
  u16x8 qf1 = *(const u16x8*)(qptr + 32 + koff);

  f32x4 acc[4] = {};
  float mrow[4], lrow[4];
#pragma unroll
  for (int r = 0; r < 4; r++) { mrow[r] = -INFINITY; lrow[r] = 0.f; }

  const float scale = 0.125f;        // 1/sqrt(64)
  u32* Vt32 = (u32*)Vt;

  for (int kt = 0; kt <= qt; ++kt) {
    const u16* Kg = K + ((size_t)(b * SEQ + kt * 64)) * DIM + h * HD;
    const u16* Vg = V + ((size_t)(b * SEQ + kt * 64)) * DIM + h * HD;

    // K+V staging: linear LDS dest, pre-swizzled global source granule (0 VGPR held)
#pragma unroll
    for (int i = 0; i < 2; i++) {
      int c = tid + i * 256;         // 512 chunks of 16B
      int r_ = c >> 3, p = c & 7;
      int ck = (p ^ swz(r_)) << 3;
      gld_lds16(Kg + (size_t)r_ * DIM + ck, &Ks[c * 8]);
      gld_lds16(Vg + (size_t)r_ * DIM + ck, &Vs[c * 8]);
    }
    __syncthreads();   // staging complete

    // packed transpose Vs -> Vt (2-way conflicts both sides)
    {
      int r0 = 2 * va, r1 = 2 * va + 1;
      u16x8 v0 = *(const u16x8*)(&Vs[r0 * 64 + ((vd ^ swz(r0)) << 3)]);
      u16x8 v1 = *(const u16x8*)(&Vs[r1 * 64 + ((vd ^ swz(r1)) << 3)]);
#pragma unroll
      for (int i = 0; i < 8; i++) {
        int d = vd * 8 + i;
        u32 val = (u32)v0[i] | ((u32)v1[i] << 16);
        Vt32[d * 32 + (((va >> 2) ^ swz(d)) << 2) + (va & 3)] = val;
      }
    }

    // S = Q K^T for this wave's 16 q-rows x 64 kv
    f32x4 sacc[4] = {};
#pragma unroll
    for (int j = 0; j < 4; j++) {
      int row = j * 16 + lr;
      int p0 = kgrp ^ swz(row);
      u16x8 kf0 = *(const u16x8*)(&Ks[row * 64 + p0 * 8]);
      u16x8 kf1 = *(const u16x8*)(&Ks[row * 64 + (p0 ^ 4) * 8]);
      sacc[j] = mfma16(qf0, kf0, sacc[j]);
      sacc[j] = mfma16(qf1, kf1, sacc[j]);
    }

    // scale + causal mask (diagonal tile only)
    float sv[4][4];
    if (kt == qt) {
#pragma unroll
      for (int j = 0; j < 4; j++)
#pragma unroll
        for (int r = 0; r < 4; r++) {
          float s = sacc[j][r] * scale;
          if (j * 16 + lr > w * 16 + kgrp * 4 + r) s = -1e30f;
          sv[j][r] = s;
        }
    } else {
#pragma unroll
      for (int j = 0; j < 4; j++)
#pragma unroll
        for (int r = 0; r < 4; r++) sv[j][r] = sacc[j][r] * scale;
    }

    // online softmax (in-place: sv becomes P)
#pragma unroll
    for (int r = 0; r < 4; r++) {
      float mx = fmaxf(fmaxf(sv[0][r], sv[1][r]), fmaxf(sv[2][r], sv[3][r]));
#pragma unroll
      for (int off = 1; off < 16; off <<= 1) mx = fmaxf(mx, __shfl_xor(mx, off, 64));
      float mnew = fmaxf(mrow[r], mx);
      float f = __expf(mrow[r] - mnew);
      mrow[r] = mnew;
      lrow[r] *= f;
#pragma unroll
      for (int j = 0; j < 4; j++) acc[j][r] *= f;
      float s0 = 0.f;
#pragma unroll
      for (int j = 0; j < 4; j++) { float p = __expf(sv[j][r] - mnew); sv[j][r] = p; s0 += p; }
#pragma unroll
      for (int off = 1; off < 16; off <<= 1) s0 += __shfl_xor(s0, off, 64);
      lrow[r] += s0;
    }

    // write P (bf16) to per-wave swizzled LDS: S-frag -> A-frag relayout
#pragma unroll
    for (int j = 0; j < 4; j++) {
      int gk = 2 * j + (lr >> 3);
#pragma unroll
      for (int r = 0; r < 4; r++) {
        int q = kgrp * 4 + r;
        Ps[w][q * 64 + ((gk ^ swz(q)) << 3) + (lr & 7)] = f2bf(sv[j][r]);
      }
    }

    __syncthreads();   // Vt + Ps visible; all Ks/Vs reads done

    // PV: O += P (16 x 64) * V (64 x 64)
#pragma unroll
    for (int ks = 0; ks < 2; ++ks) {
      int g = ks * 4 + kgrp;
      u16x8 pa = *(const u16x8*)(&Ps[w][lr * 64 + ((g ^ swz(lr)) << 3)]);
#pragma unroll
      for (int j = 0; j < 4; j++) {
        int d = j * 16 + lr;
        u16x8 vb = *(const u16x8*)(&Vt[d * 64 + ((g ^ swz(d)) << 3)]);
        acc[j] = mfma16(pa, vb, acc[j]);
      }
    }
    // no tail barrier: next-iter staging only overwrites Ks/Vs (reads finished
    // pre-bar2 by all waves); next-iter Vt writes are after next bar1.
  }

  // normalize + store (B,S,D) layout at [b*S + q][h*64 + d]
  const size_t rowbase = (size_t)(b * SEQ + q0 + w * 16);
#pragma unroll
  for (int r = 0; r < 4; r++) {
    float inv = 1.f / lrow[r];
    u16* op = O + (rowbase + kgrp * 4 + r) * DIM + h * HD;
#pragma unroll
    for (int j = 0; j < 4; j++) op[j * 16 + lr] = f2bf(acc[j][r] * inv);
  }
}

// ---------------- host launcher ----------------
extern "C" void kernel_launch(void* const* d_in, const int* in_sizes, int n_in,
                              void* d_out, int out_size, void* d_ws, size_t ws_size,
                              hipStream_t stream) {
  const float* x  = (const float*)d_in[0];
  const float* Wq = (const float*)d_in[1];
  const float* Wk = (const float*)d_in[2];
  const float* Wv = (const float*)d_in[3];
  const float* Wo = (const float*)d_in[4];
  float* out = (float*)d_out;

  char* ws = (char*)d_ws;
  u16* xb    = (u16*)(ws);
  u16* qb    = (u16*)(ws + 16777216);
  u16* kb    = (u16*)(ws + 33554432);
  u16* vb    = (u16*)(ws + 50331648);
  u16* attnb = (u16*)(ws + 67108864);
  u16* wqb   = (u16*)(ws + 83886080);            // wq,wk,wv,wo contiguous
  u16* wkb   = (u16*)(ws + 85983232);
  u16* wvb   = (u16*)(ws + 88080384);
  u16* wob   = (u16*)(ws + 90177536);
  float* ctab = (float*)(ws + 92274688);
  float* stab = (float*)(ws + 92340224);

  const int nx = MROWS * DIM;        // 8388608
  const int nw = DIM * DIM;          // 1048576

  f32_to_bf16_kernel<<<nx / 4 / 256, 256, 0, stream>>>(x, xb, nx);
  wconv_kernel<<<dim3(nw / 4 / 256, 1, 4), 256, 0, stream>>>(Wq, Wk, Wv, Wo, wqb);
  rope_tables_kernel<<<SEQ * 32 / 256, 256, 0, stream>>>(ctab, stab);

  // fused QKV projection: [8192][1024] x [3072][1024]^T, 1536 blocks
  gemm_qkv<<<1536, 256, 0, stream>>>(xb, wqb, qb, kb, vb);

  rope_kernel<<<dim3(MROWS * NH * 4 / 256, 1, 2), 256, 0, stream>>>(qb, kb, ctab, stab);

  attn_kernel<<<2048, 256, 0, stream>>>(qb, kb, vb, attnb);

  gemm_out<<<512, 256, 0, stream>>>(attnb, wob, out);
}

// Round 8
// 249.194 us; speedup vs baseline: 1.3925x; 1.3925x over previous
//
#include <hip/hip_runtime.h>

#define DIM 1024
#define NH 16
#define HD 64
#define BATCH 16
#define SEQ 512
#define MROWS (BATCH*SEQ)   // 8192

using u16 = unsigned short;
using u32 = unsigned int;
typedef __attribute__((ext_vector_type(8))) u16 u16x8;
typedef __attribute__((ext_vector_type(4))) u16 u16x4;
typedef __attribute__((ext_vector_type(8))) __bf16 bf16x8;
typedef __attribute__((ext_vector_type(4))) float f32x4;
typedef __attribute__((ext_vector_type(4))) float float4v;

__device__ __forceinline__ float bf2f(u16 h) {
  unsigned u = ((unsigned)h) << 16;
  union { unsigned u; float f; } v; v.u = u; return v.f;
}
__device__ __forceinline__ u16 f2bf(float f) {
  union { float f; unsigned u; } v; v.f = f;
  unsigned u = v.u + 0x7fffu + ((v.u >> 16) & 1u);
  return (u16)(u >> 16);
}
// granule swizzle for 64-u16 rows (8 granules of 16B)
__device__ __forceinline__ int swz(int r) { return (r & 7) ^ (r >> 3); }

// async global->LDS, 16B per lane. LDS dest must be wave-uniform base + lane*16.
__device__ __forceinline__ void gld_lds16(const u16* g, u16* l) {
  __builtin_amdgcn_global_load_lds(
      (const __attribute__((address_space(1))) void*)g,
      (__attribute__((address_space(3))) void*)l, 16, 0, 0);
}

__device__ __forceinline__ f32x4 mfma16(u16x8 a, u16x8 b, f32x4 c) {
  return __builtin_amdgcn_mfma_f32_16x16x32_bf16(
      __builtin_bit_cast(bf16x8, a), __builtin_bit_cast(bf16x8, b), c, 0, 0, 0);
}

// ---------------- fp32 -> bf16 conversion ----------------
__global__ void f32_to_bf16_kernel(const float* __restrict__ in, u16* __restrict__ out, int n) {
  int i = (blockIdx.x * blockDim.x + threadIdx.x) * 4;
  if (i >= n) return;
  float4v v = *(const float4v*)(in + i);
  u16x4 o;
  o.x = f2bf(v.x); o.y = f2bf(v.y); o.z = f2bf(v.z); o.w = f2bf(v.w);
  *(u16x4*)(out + i) = o;
}

// fused conversion of the 4 weight matrices (outputs contiguous in ws)
__global__ void wconv_kernel(const float* __restrict__ Wq, const float* __restrict__ Wk,
                             const float* __restrict__ Wv, const float* __restrict__ Wo,
                             u16* __restrict__ out) {
  const float* in = (blockIdx.z == 0) ? Wq : (blockIdx.z == 1) ? Wk
                   : (blockIdx.z == 2) ? Wv : Wo;
  int i = (blockIdx.x * blockDim.x + threadIdx.x) * 4;
  float4v v = *(const float4v*)(in + i);
  u16x4 o;
  o.x = f2bf(v.x); o.y = f2bf(v.y); o.z = f2bf(v.z); o.w = f2bf(v.w);
  *(u16x4*)(out + (size_t)blockIdx.z * (DIM * DIM) + i) = o;
}

// ---------------- RoPE tables: [SEQ][32] cos/sin ----------------
__global__ void rope_tables_kernel(float* __restrict__ ctab, float* __restrict__ stab) {
  int t = blockIdx.x * blockDim.x + threadIdx.x;  // SEQ*32
  int s = t >> 5, j = t & 31;
  float invf = powf(10000.f, -(float)j / 32.f);
  float a = (float)s * invf;
  ctab[t] = cosf(a);
  stab[t] = sinf(a);
}

// ---------------- RoPE applied in-place to q and k (bf16) ----------------
__global__ void rope_kernel(u16* __restrict__ Q, u16* __restrict__ K,
                            const float* __restrict__ ctab, const float* __restrict__ stab) {
  int t = blockIdx.x * blockDim.x + threadIdx.x;  // 524288 per tensor
  u16* X = blockIdx.z ? K : Q;
  int j = t & 3;
  int h = (t >> 2) & 15;
  int m = t >> 6;
  int s = m & (SEQ - 1);
  u16* base = X + (size_t)m * DIM + h * HD + j * 8;
  u16x8 lo = *(u16x8*)base;
  u16x8 hi = *(u16x8*)(base + 32);
  const float* cp = ctab + s * 32 + j * 8;
  const float* sp = stab + s * 32 + j * 8;
  u16x8 lo2, hi2;
#pragma unroll
  for (int i = 0; i < 8; i++) {
    float c = cp[i], sn = sp[i];
    float xl = bf2f(lo[i]), xh = bf2f(hi[i]);
    lo2[i] = f2bf(xl * c - xh * sn);
    hi2[i] = f2bf(xh * c + xl * sn);
  }
  *(u16x8*)base = lo2;
  *(u16x8*)(base + 32) = hi2;
}

// ---------------- GEMM 128x128 tile, BK=64, swizzled LDS, XCD-chunked ----------------
// C[m][n] = sum_k A[m][k]*B[n][k].
#define BM 128
#define BN 128

// fused QKV: Bw = [3072][1024]; output select by column block
__global__ __launch_bounds__(256, 4) void gemm_qkv(const u16* __restrict__ A,
                                                   const u16* __restrict__ Bw,
                                                   u16* __restrict__ Cq, u16* __restrict__ Ck,
                                                   u16* __restrict__ Cv) {
  __shared__ alignas(16) u16 As[BM * 64];
  __shared__ alignas(16) u16 Bs[BN * 64];
  const int K = DIM, N = DIM;
  // XCD-chunked swizzle: nwg=1536, chunk=192, NBX=24
  const int orig = blockIdx.x;
  const int id2 = (orig & 7) * 192 + (orig >> 3);
  const int m0 = (id2 / 24) * BM;
  const int n0g = (id2 % 24) * BN;                 // 0..3071
  u16* C = (n0g < 1024) ? Cq : (n0g < 2048) ? Ck : Cv;
  const int n0 = n0g & 1023;
  const int tid = threadIdx.x, lane = tid & 63;
  const int w = tid >> 6, wr = w >> 1, wc = w & 1;
  const int lr = lane & 15, kgrp = lane >> 4;

  f32x4 acc[4][4] = {};

  for (int kt = 0; kt < K; kt += 64) {
#pragma unroll
    for (int i = 0; i < 4; i++) {                  // A: 1024 granules of 16B
      int c = tid + i * 256;
      int r_ = c >> 3, p = c & 7;
      gld_lds16(A + (size_t)(m0 + r_) * K + kt + ((p ^ (r_ & 7)) << 3), &As[c * 8]);
    }
#pragma unroll
    for (int i = 0; i < 4; i++) {                  // B: 1024 granules of 16B
      int c = tid + i * 256;
      int r_ = c >> 3, p = c & 7;
      gld_lds16(Bw + (size_t)(n0g + r_) * K + kt + ((p ^ (r_ & 7)) << 3), &Bs[c * 8]);
    }
    __syncthreads();
#pragma unroll
    for (int half = 0; half < 2; half++) {
      u16x8 a[4], b[4];
      int g = half * 4 + kgrp;
#pragma unroll
      for (int i = 0; i < 4; i++) {
        int row = wr * 64 + i * 16 + lr;
        a[i] = *(const u16x8*)(&As[row * 64 + ((g ^ (row & 7)) << 3)]);
      }
#pragma unroll
      for (int j = 0; j < 4; j++) {
        int row = wc * 64 + j * 16 + lr;
        b[j] = *(const u16x8*)(&Bs[row * 64 + ((g ^ (row & 7)) << 3)]);
      }
#pragma unroll
      for (int i = 0; i < 4; i++)
#pragma unroll
        for (int j = 0; j < 4; j++)
          acc[i][j] = mfma16(a[i], b[j], acc[i][j]);
    }
    __syncthreads();
  }

#pragma unroll
  for (int i = 0; i < 4; i++) {
    int grow = m0 + wr * 64 + i * 16 + kgrp * 4;
#pragma unroll
    for (int j = 0; j < 4; j++) {
      int gcol = n0 + wc * 64 + j * 16 + lr;
#pragma unroll
      for (int r = 0; r < 4; r++)
        C[(size_t)(grow + r) * N + gcol] = f2bf(acc[i][j][r]);
    }
  }
}

// out projection: C fp32 [8192][1024]; nwg=512, chunk=64, NBX=8
__global__ __launch_bounds__(256, 4) void gemm_out(const u16* __restrict__ A,
                                                   const u16* __restrict__ B,
                                                   float* __restrict__ C) {
  __shared__ alignas(16) u16 As[BM * 64];
  __shared__ alignas(16) u16 Bs[BN * 64];
  const int K = DIM, N = DIM;
  const int orig = blockIdx.x;
  const int id2 = (orig & 7) * 64 + (orig >> 3);
  const int m0 = (id2 >> 3) * BM;
  const int n0 = (id2 & 7) * BN;
  const int tid = threadIdx.x, lane = tid & 63;
  const int w = tid >> 6, wr = w >> 1, wc = w & 1;
  const int lr = lane & 15, kgrp = lane >> 4;

  f32x4 acc[4][4] = {};

  for (int kt = 0; kt < K; kt += 64) {
#pragma unroll
    for (int i = 0; i < 4; i++) {
      int c = tid + i * 256;
      int r_ = c >> 3, p = c & 7;
      gld_lds16(A + (size_t)(m0 + r_) * K + kt + ((p ^ (r_ & 7)) << 3), &As[c * 8]);
    }
#pragma unroll
    for (int i = 0; i < 4; i++) {
      int c = tid + i * 256;
      int r_ = c >> 3, p = c & 7;
      gld_lds16(B + (size_t)(n0 + r_) * K + kt + ((p ^ (r_ & 7)) << 3), &Bs[c * 8]);
    }
    __syncthreads();
#pragma unroll
    for (int half = 0; half < 2; half++) {
      u16x8 a[4], b[4];
      int g = half * 4 + kgrp;
#pragma unroll
      for (int i = 0; i < 4; i++) {
        int row = wr * 64 + i * 16 + lr;
        a[i] = *(const u16x8*)(&As[row * 64 + ((g ^ (row & 7)) << 3)]);
      }
#pragma unroll
      for (int j = 0; j < 4; j++) {
        int row = wc * 64 + j * 16 + lr;
        b[j] = *(const u16x8*)(&Bs[row * 64 + ((g ^ (row & 7)) << 3)]);
      }
#pragma unroll
      for (int i = 0; i < 4; i++)
#pragma unroll
        for (int j = 0; j < 4; j++)
          acc[i][j] = mfma16(a[i], b[j], acc[i][j]);
    }
    __syncthreads();
  }

#pragma unroll
  for (int i = 0; i < 4; i++) {
    int grow = m0 + wr * 64 + i * 16 + kgrp * 4;
#pragma unroll
    for (int j = 0; j < 4; j++) {
      int gcol = n0 + wc * 64 + j * 16 + lr;
#pragma unroll
      for (int r = 0; r < 4; r++)
        C[(size_t)(grow + r) * N + gcol] = acc[i][j][r];
    }
  }
}

// ---------------- Flash attention v4 (causal), swizzled LDS, no-spill ----------------
// 1D grid 2048 (XCD-chunked). Block: 256 threads = 4 waves; wave w owns 16 q rows.
// launch_bounds (256,4): VGPR cap 128 > ~90 working set -> no scratch spills
// (round 7 post-mortem: (256,5) capped ~102 but allocator spilled to 48 + 300MB
//  of scratch traffic -> HBM-bound).
__global__ __launch_bounds__(256, 4) void attn_kernel(const u16* __restrict__ Q,
                                                      const u16* __restrict__ K,
                                                      const u16* __restrict__ V,
                                                      u16* __restrict__ O) {
  __shared__ alignas(16) u16 Ks[64 * 64];
  __shared__ alignas(16) u16 Vs[64 * 64];
  __shared__ alignas(16) u16 Vt[64 * 64];
  __shared__ alignas(16) u16 Ps[4][16 * 64];

  const int orig = blockIdx.x;                 // 2048 blocks
  const int id2 = (orig & 7) * 256 + (orig >> 3);
  const int qt = id2 & 7, bh = id2 >> 3;
  const int b = bh >> 4, h = bh & 15;
  const int tid = threadIdx.x, lane = tid & 63, w = tid >> 6;
  const int lr = lane & 15, kgrp = lane >> 4, koff = kgrp * 8;
  const int q0 = qt * 64;
  const int va = tid >> 3;          // kv-pair index 0..31 (transpose role)
  const int vd = tid & 7;           // d granule 0..7

  // Q fragments, held in registers the whole kernel
  const u16* qptr = Q + ((size_t)(b * SEQ + q0 + w * 16 + lr)) * DIM + h * HD;
  u16x8 qf0 = *(const u16x8*)(qptr + koff);
  u16x8 qf1 = *(const u16x8*)(qptr + 32 + koff);

  f32x4 acc[4] = {};
  float mrow[4], lrow[4];
#pragma unroll
  for (int r = 0; r < 4; r++) { mrow[r] = -INFINITY; lrow[r] = 0.f; }

  const float scale = 0.125f;        // 1/sqrt(64)
  u32* Vt32 = (u32*)Vt;

  for (int kt = 0; kt <= qt; ++kt) {
    const u16* Kg = K + ((size_t)(b * SEQ + kt * 64)) * DIM + h * HD;
    const u16* Vg = V + ((size_t)(b * SEQ + kt * 64)) * DIM + h * HD;

    // K+V staging: linear LDS dest, pre-swizzled global source granule (0 VGPR held)
#pragma unroll
    for (int i = 0; i < 2; i++) {
      int c = tid + i * 256;         // 512 chunks of 16B
      int r_ = c >> 3, p = c & 7;
      int ck = (p ^ swz(r_)) << 3;
      gld_lds16(Kg + (size_t)r_ * DIM + ck, &Ks[c * 8]);
      gld_lds16(Vg + (size_t)r_ * DIM + ck, &Vs[c * 8]);
    }
    __syncthreads();   // staging complete

    // packed transpose Vs -> Vt (2-way conflicts both sides)
    {
      int r0 = 2 * va, r1 = 2 * va + 1;
      u16x8 v0 = *(const u16x8*)(&Vs[r0 * 64 + ((vd ^ swz(r0)) << 3)]);
      u16x8 v1 = *(const u16x8*)(&Vs[r1 * 64 + ((vd ^ swz(r1)) << 3)]);
#pragma unroll
      for (int i = 0; i < 8; i++) {
        int d = vd * 8 + i;
        u32 val = (u32)v0[i] | ((u32)v1[i] << 16);
        Vt32[d * 32 + (((va >> 2) ^ swz(d)) << 2) + (va & 3)] = val;
      }
    }

    // S = Q K^T for this wave's 16 q-rows x 64 kv (kept in sacc, reused as P)
    f32x4 sacc[4] = {};
#pragma unroll
    for (int j = 0; j < 4; j++) {
      int row = j * 16 + lr;
      int p0 = kgrp ^ swz(row);
      u16x8 kf0 = *(const u16x8*)(&Ks[row * 64 + p0 * 8]);
      u16x8 kf1 = *(const u16x8*)(&Ks[row * 64 + (p0 ^ 4) * 8]);
      sacc[j] = mfma16(qf0, kf0, sacc[j]);
      sacc[j] = mfma16(qf1, kf1, sacc[j]);
    }

    // scale + causal mask in place (diagonal tile only)
    if (kt == qt) {
#pragma unroll
      for (int j = 0; j < 4; j++)
#pragma unroll
        for (int r = 0; r < 4; r++) {
          float s = sacc[j][r] * scale;
          if (j * 16 + lr > w * 16 + kgrp * 4 + r) s = -1e30f;
          sacc[j][r] = s;
        }
    } else {
#pragma unroll
      for (int j = 0; j < 4; j++)
#pragma unroll
        for (int r = 0; r < 4; r++) sacc[j][r] *= scale;
    }

    // online softmax, in place: sacc becomes P
#pragma unroll
    for (int r = 0; r < 4; r++) {
      float mx = fmaxf(fmaxf(sacc[0][r], sacc[1][r]), fmaxf(sacc[2][r], sacc[3][r]));
#pragma unroll
      for (int off = 1; off < 16; off <<= 1) mx = fmaxf(mx, __shfl_xor(mx, off, 64));
      float mnew = fmaxf(mrow[r], mx);
      float f = __expf(mrow[r] - mnew);
      mrow[r] = mnew;
      lrow[r] *= f;
#pragma unroll
      for (int j = 0; j < 4; j++) acc[j][r] *= f;
      float s0 = 0.f;
#pragma unroll
      for (int j = 0; j < 4; j++) { float p = __expf(sacc[j][r] - mnew); sacc[j][r] = p; s0 += p; }
#pragma unroll
      for (int off = 1; off < 16; off <<= 1) s0 += __shfl_xor(s0, off, 64);
      lrow[r] += s0;
    }

    // write P (bf16) to per-wave swizzled LDS: S-frag -> A-frag relayout
#pragma unroll
    for (int j = 0; j < 4; j++) {
      int gk = 2 * j + (lr >> 3);
#pragma unroll
      for (int r = 0; r < 4; r++) {
        int q = kgrp * 4 + r;
        Ps[w][q * 64 + ((gk ^ swz(q)) << 3) + (lr & 7)] = f2bf(sacc[j][r]);
      }
    }

    __syncthreads();   // Vt + Ps visible; all Ks/Vs reads done

    // PV: O += P (16 x 64) * V (64 x 64)
#pragma unroll
    for (int ks = 0; ks < 2; ++ks) {
      int g = ks * 4 + kgrp;
      u16x8 pa = *(const u16x8*)(&Ps[w][lr * 64 + ((g ^ swz(lr)) << 3)]);
#pragma unroll
      for (int j = 0; j < 4; j++) {
        int d = j * 16 + lr;
        u16x8 vb = *(const u16x8*)(&Vt[d * 64 + ((g ^ swz(d)) << 3)]);
        acc[j] = mfma16(pa, vb, acc[j]);
      }
    }
    // no tail barrier: next-iter staging only overwrites Ks/Vs (reads finished
    // pre-bar2 by all waves); next-iter Vt writes are after next bar1.
  }

  // normalize + store (B,S,D) layout at [b*S + q][h*64 + d]
  const size_t rowbase = (size_t)(b * SEQ + q0 + w * 16);
#pragma unroll
  for (int r = 0; r < 4; r++) {
    float inv = 1.f / lrow[r];
    u16* op = O + (rowbase + kgrp * 4 + r) * DIM + h * HD;
#pragma unroll
    for (int j = 0; j < 4; j++) op[j * 16 + lr] = f2bf(acc[j][r] * inv);
  }
}

// ---------------- host launcher ----------------
extern "C" void kernel_launch(void* const* d_in, const int* in_sizes, int n_in,
                              void* d_out, int out_size, void* d_ws, size_t ws_size,
                              hipStream_t stream) {
  const float* x  = (const float*)d_in[0];
  const float* Wq = (const float*)d_in[1];
  const float* Wk = (const float*)d_in[2];
  const float* Wv = (const float*)d_in[3];
  const float* Wo = (const float*)d_in[4];
  float* out = (float*)d_out;

  char* ws = (char*)d_ws;
  u16* xb    = (u16*)(ws);
  u16* qb    = (u16*)(ws + 16777216);
  u16* kb    = (u16*)(ws + 33554432);
  u16* vb    = (u16*)(ws + 50331648);
  u16* attnb = (u16*)(ws + 67108864);
  u16* wqb   = (u16*)(ws + 83886080);            // wq,wk,wv,wo contiguous
  u16* wkb   = (u16*)(ws + 85983232);
  u16* wvb   = (u16*)(ws + 88080384);
  u16* wob   = (u16*)(ws + 90177536);
  float* ctab = (float*)(ws + 92274688);
  float* stab = (float*)(ws + 92340224);

  const int nx = MROWS * DIM;        // 8388608
  const int nw = DIM * DIM;          // 1048576

  f32_to_bf16_kernel<<<nx / 4 / 256, 256, 0, stream>>>(x, xb, nx);
  wconv_kernel<<<dim3(nw / 4 / 256, 1, 4), 256, 0, stream>>>(Wq, Wk, Wv, Wo, wqb);
  rope_tables_kernel<<<SEQ * 32 / 256, 256, 0, stream>>>(ctab, stab);

  // fused QKV projection: [8192][1024] x [3072][1024]^T, 1536 blocks
  gemm_qkv<<<1536, 256, 0, stream>>>(xb, wqb, qb, kb, vb);

  rope_kernel<<<dim3(MROWS * NH * 4 / 256, 1, 2), 256, 0, stream>>>(qb, kb, ctab, stab);

  attn_kernel<<<2048, 256, 0, stream>>>(qb, kb, vb, attnb);

  gemm_out<<<512, 256, 0, stream>>>(attnb, wob, out);
}